// Round 10
// baseline (129.549 us; speedup 1.0000x reference)
//
#include <hip/hip_runtime.h>
#include <hip/hip_bf16.h>

// 3x3 VALID conv via bf16 MFMA implicit GEMM.
// x: (64,224,224) fp32, w: (128,64,3,3) fp32, out: (128,222,222) fp32.
//
// R10: MEASUREMENT ROUND on the R9 structure. The tap loop runs REP=4
// times (acc = 4x result, epilogue scales by 0.25 — exact). Purpose:
// (a) cold conv dispatch inflates past the ~43us poison-fill cutoff so
// rocprof's top-5 finally shows conv's counters; (b) warm-delta
// discriminates loop-body-bound (dur ~140) vs per-block-overhead-bound
// (dur ~100). R7 and R9's very different designs both landed at conv~18us
// while models say ~5 — stop guessing, measure.

#define H_IN   224
#define W_IN   224
#define C_OUT  128
#define H_OUT  222
#define W_OUT  222
#define XP     226   // padded spatial extent of xt
#define CPAD   72    // padded c stride in conv x-LDS
#define TW     68    // padded w stride in transpose LDS
#define REP    4     // inner repeat factor (measurement)

typedef __attribute__((ext_vector_type(8)))  short bf16x8;
typedef __attribute__((ext_vector_type(16))) float f32x16;

static __device__ __forceinline__ unsigned short f2bs(float f) {
    union { __hip_bfloat16 h; unsigned short u; } cv;
    cv.h = __float2bfloat16(f);
    return cv.u;
}

// wt layout: [ij][kstep(=c>>3)][co][c&7]  -> A-fragment reads lane-contiguous.
__global__ __launch_bounds__(256)
void transform_w_kernel(const float* __restrict__ w, __hip_bfloat16* __restrict__ wt)
{
    int idx = blockIdx.x * 256 + threadIdx.x;     // 9*128*64 = 73,728
    if (idx < 9 * 128 * 64) {
        int ij  = idx >> 13;
        int rem = idx & 8191;
        int co  = rem >> 6;
        int c   = rem & 63;
        wt[((ij * 8 + (c >> 3)) * 128 + co) * 8 + (c & 7)] =
            __float2bfloat16(w[(co * 64 + c) * 9 + ij]);
    }
}

__global__ __launch_bounds__(256)
void transpose_x_kernel(const float* __restrict__ x, __hip_bfloat16* __restrict__ xt)
{
    __shared__ __align__(16) unsigned short tile[64 * TW];   // [c][w_local]
    const int h  = blockIdx.y;                 // 0..225
    const int w0 = blockIdx.x * 64;            // 0,64,128,192
    const int t  = threadIdx.x;

    // Phase 1: coalesced float4 reads along w; zeros for padded h/w.
    {
        const int wq = (t & 15) * 4;           // 0..60 (lanes contiguous in w)
        const int c0 = t >> 4;                 // 0..15
        #pragma unroll
        for (int p = 0; p < 4; ++p) {
            const int c  = c0 + p * 16;
            const int wg = w0 + wq;
            float4 v = make_float4(0.f, 0.f, 0.f, 0.f);
            if (h < H_IN && wg < W_IN)         // wg%4==0, W_IN%4==0 -> all-or-nothing
                v = *(const float4*)(x + ((size_t)c * H_IN + h) * W_IN + wg);
            ushort4 b;
            b.x = f2bs(v.x); b.y = f2bs(v.y); b.z = f2bs(v.z); b.w = f2bs(v.w);
            *(ushort4*)(tile + c * TW + wq) = b;   // (c*136 + wq*2) % 8 == 0
        }
    }
    __syncthreads();

    // Phase 2: gather 16 c per thread from LDS, contiguous 16B/lane stores.
    {
        const int wl = t >> 2;                 // 0..63
        const int cq = (t & 3) * 16;           // 0,16,32,48
        const int wg = w0 + wl;
        if (wg < XP) {
            alignas(16) unsigned short r[16];
            #pragma unroll
            for (int k = 0; k < 16; ++k)
                r[k] = tile[(cq + k) * TW + wl];
            float4* d = (float4*)((unsigned short*)xt + ((size_t)h * XP + wg) * 64 + cq);
            d[0] = ((const float4*)r)[0];
            d[1] = ((const float4*)r)[1];
        }
    }
}

__global__ __launch_bounds__(256)
void conv_mfma_kernel(const __hip_bfloat16* __restrict__ xt,
                      const __hip_bfloat16* __restrict__ wt,
                      float* __restrict__ out)
{
    __shared__ __hip_bfloat16 xs[10 * 34 * CPAD];   // [row][wc][c]  48,960 B
    __shared__ __hip_bfloat16 wsb[2][8 * 64 * 8];   // [buf][kstep][co][c8] 2x8,192 B
    const int ow0 = blockIdx.x * 32;
    const int oh0 = blockIdx.y * 8;
    const int co0 = blockIdx.z * 64;
    const int tid = threadIdx.x;

    // Stage x tile: rows oh0..oh0+9, cols ow0..ow0+33, all 64 c (bf16).
    for (int q = tid; q < 10 * 34 * 8; q += 256) {
        int sub = q & 7;
        int pix = q >> 3;
        int row = pix / 34;
        int wc  = pix - row * 34;
        *(float4*)(xs + (row * 34 + wc) * CPAD + sub * 8) =
            *(const float4*)(xt + ((oh0 + row) * XP + (ow0 + wc)) * 64 + sub * 8);
    }
    // Stage tap 0 weights (this block's 64 co): 8,192 B, lane-contiguous.
    #pragma unroll
    for (int k = 0; k < 2; ++k) {
        int q  = k * 256 + tid;          // 512 chunks of 16B
        int ks = q >> 6;                 // kstep 0..7
        int cc = q & 63;                 // co 0..63
        *(float4*)(&wsb[0][(ks * 64 + cc) * 8]) =
            *(const float4*)(wt + ((0 * 8 + ks) * 128 + co0 + cc) * 8);
    }
    __syncthreads();

    const int wave = tid >> 6;
    const int lane = tid & 63;
    const int n    = lane & 31;     // A: co offset; B: ow offset; D: col
    const int h    = lane >> 5;     // k-half selector
    const int r0   = wave * 2;      // this wave's 2 output rows

    f32x16 acc[2][2] = {};          // [mi][ni]

    for (int rep = 0; rep < REP; ++rep) {
        #pragma unroll
        for (int p = 0; p < 9; ++p) {   // tap index = i*3 + jj
            const int i  = p / 3;
            const int jj = p - i * 3;
            const int q9 = rep * 9 + p;     // linear tap counter
            const int cb = q9 & 1;

            // Prefetch the next tap (cyclic across reps) into the other buffer.
            float4 pf[2];
            int ks0 = 0, cc0 = 0, ks1 = 0, cc1 = 0;
            const bool do_pf = (q9 < REP * 9 - 1);
            const int  np    = (p + 1 == 9) ? 0 : (p + 1);
            if (do_pf) {
                #pragma unroll
                for (int k = 0; k < 2; ++k) {
                    int q  = k * 256 + tid;
                    int ks = q >> 6;
                    int cc = q & 63;
                    pf[k] = *(const float4*)(wt + ((np * 8 + ks) * 128 + co0 + cc) * 8);
                    if (k == 0) { ks0 = ks; cc0 = cc; } else { ks1 = ks; cc1 = cc; }
                }
            }

            // Compute tap p: 4 k-steps, mi=2 x ni=2 register tile.
            #pragma unroll
            for (int t = 0; t < 4; ++t) {
                bf16x8 afr[2], bfr[2];
                #pragma unroll
                for (int mi = 0; mi < 2; ++mi)
                    afr[mi] = *(const bf16x8*)(&wsb[cb][((t * 2 + h) * 64 + mi * 32 + n) * 8]);
                #pragma unroll
                for (int ni = 0; ni < 2; ++ni)
                    bfr[ni] = *(const bf16x8*)(xs +
                        ((i + r0 + ni) * 34 + n + jj) * CPAD + t * 16 + h * 8);
                #pragma unroll
                for (int mi = 0; mi < 2; ++mi)
                    #pragma unroll
                    for (int ni = 0; ni < 2; ++ni)
                        acc[mi][ni] = __builtin_amdgcn_mfma_f32_32x32x16_bf16(
                            afr[mi], bfr[ni], acc[mi][ni], 0, 0, 0);
            }

            if (do_pf) {
                *(float4*)(&wsb[1 - cb][(ks0 * 64 + cc0) * 8]) = pf[0];
                *(float4*)(&wsb[1 - cb][(ks1 * 64 + cc1) * 8]) = pf[1];
            }
            __syncthreads();
        }
    }

    // Epilogue: scale by 1/REP (exact); lanes 0..31 = 32 consecutive ow.
    #pragma unroll
    for (int mi = 0; mi < 2; ++mi) {
        #pragma unroll
        for (int ni = 0; ni < 2; ++ni) {
            const int oh = oh0 + r0 + ni;
            const int ow = ow0 + n;
            if (oh < H_OUT && ow < W_OUT) {
                #pragma unroll
                for (int r = 0; r < 16; ++r) {
                    int co = co0 + mi * 32 + (r & 3) + 8 * (r >> 2) + 4 * h;
                    out[(size_t)co * (H_OUT * W_OUT) + oh * W_OUT + ow] =
                        acc[mi][ni][r] * (1.0f / REP);
                }
            }
        }
    }
}

extern "C" void kernel_launch(void* const* d_in, const int* in_sizes, int n_in,
                              void* d_out, int out_size, void* d_ws, size_t ws_size,
                              hipStream_t stream)
{
    const float* x = (const float*)d_in[0];
    const float* w = (const float*)d_in[1];
    float* out     = (float*)d_out;

    __hip_bfloat16* xt = (__hip_bfloat16*)d_ws;                      // 226*226*64*2 B
    __hip_bfloat16* wt = (__hip_bfloat16*)((char*)d_ws + (size_t)XP * XP * 64 * 2);

    transform_w_kernel<<<288, 256, 0, stream>>>(w, wt);
    transpose_x_kernel<<<dim3(4, XP), 256, 0, stream>>>(x, xt);
    conv_mfma_kernel<<<dim3(7, 28, 2), 256, 0, stream>>>(xt, wt, out);
}

// Round 11
// 91.933 us; speedup vs baseline: 1.4092x; 1.4092x over previous
//
#include <hip/hip_runtime.h>
#include <hip/hip_bf16.h>

// 3x3 VALID conv via bf16 MFMA implicit GEMM.
// x: (64,224,224) fp32, w: (128,64,3,3) fp32, out: (128,222,222) fp32.
//
// R11: R10's measurement closed the model — conv was LDS-pipe-bound
// (0.0625 B/MAC vs 0.0104 sustainable -> MfmaUtil ceiling 16.6%, measured
// 17.6%) at 2 blocks/CU. Fix: (a) weights read directly from global wt
// (lane-contiguous [ij][kstep][co][c8] layout -> coalesced 1KB/instr,
// L1/L2-hot, 8 independent loads batched per tap, tap loop fully unrolled,
// ZERO barriers after staging) — A-traffic moves to the VMEM/L1 pipe,
// parallel to LDS; (b) xs shrunk to CPAD=64 + XOR chunk swizzle
// (conflict-free, 16B-aligned) = 43,520 B -> 3 blocks/CU (12 waves TLP).
// A: m=lane&31(co), k=(lane>>5)*8+j. B: n=lane&31(ow). D: col=lane&31,
// row=(reg&3)+8*(reg>>2)+4*(lane>>5)  [m74/m101-verified, R9-validated].

#define H_IN   224
#define W_IN   224
#define C_OUT  128
#define H_OUT  222
#define W_OUT  222
#define XP     226   // padded spatial extent of xt
#define TW     68    // padded w stride in transpose LDS

typedef __attribute__((ext_vector_type(8)))  short bf16x8;
typedef __attribute__((ext_vector_type(16))) float f32x16;

static __device__ __forceinline__ unsigned short f2bs(float f) {
    union { __hip_bfloat16 h; unsigned short u; } cv;
    cv.h = __float2bfloat16(f);
    return cv.u;
}

// wt layout: [ij][kstep(=c>>3)][co][c&7]  -> A-fragment reads lane-contiguous.
__global__ __launch_bounds__(256)
void transform_w_kernel(const float* __restrict__ w, __hip_bfloat16* __restrict__ wt)
{
    int idx = blockIdx.x * 256 + threadIdx.x;     // 9*128*64 = 73,728
    if (idx < 9 * 128 * 64) {
        int ij  = idx >> 13;
        int rem = idx & 8191;
        int co  = rem >> 6;
        int c   = rem & 63;
        wt[((ij * 8 + (c >> 3)) * 128 + co) * 8 + (c & 7)] =
            __float2bfloat16(w[(co * 64 + c) * 9 + ij]);
    }
}

__global__ __launch_bounds__(256)
void transpose_x_kernel(const float* __restrict__ x, __hip_bfloat16* __restrict__ xt)
{
    __shared__ __align__(16) unsigned short tile[64 * TW];   // [c][w_local]
    const int h  = blockIdx.y;                 // 0..225
    const int w0 = blockIdx.x * 64;            // 0,64,128,192
    const int t  = threadIdx.x;

    // Phase 1: coalesced float4 reads along w; zeros for padded h/w.
    {
        const int wq = (t & 15) * 4;           // 0..60 (lanes contiguous in w)
        const int c0 = t >> 4;                 // 0..15
        #pragma unroll
        for (int p = 0; p < 4; ++p) {
            const int c  = c0 + p * 16;
            const int wg = w0 + wq;
            float4 v = make_float4(0.f, 0.f, 0.f, 0.f);
            if (h < H_IN && wg < W_IN)         // wg%4==0, W_IN%4==0 -> all-or-nothing
                v = *(const float4*)(x + ((size_t)c * H_IN + h) * W_IN + wg);
            ushort4 b;
            b.x = f2bs(v.x); b.y = f2bs(v.y); b.z = f2bs(v.z); b.w = f2bs(v.w);
            *(ushort4*)(tile + c * TW + wq) = b;   // (c*136 + wq*2) % 8 == 0
        }
    }
    __syncthreads();

    // Phase 2: gather 16 c per thread from LDS, contiguous 16B/lane stores.
    {
        const int wl = t >> 2;                 // 0..63
        const int cq = (t & 3) * 16;           // 0,16,32,48
        const int wg = w0 + wl;
        if (wg < XP) {
            alignas(16) unsigned short r[16];
            #pragma unroll
            for (int k = 0; k < 16; ++k)
                r[k] = tile[(cq + k) * TW + wl];
            float4* d = (float4*)((unsigned short*)xt + ((size_t)h * XP + wg) * 64 + cq);
            d[0] = ((const float4*)r)[0];
            d[1] = ((const float4*)r)[1];
        }
    }
}

__global__ __launch_bounds__(256)
void conv_mfma_kernel(const __hip_bfloat16* __restrict__ xt,
                      const __hip_bfloat16* __restrict__ wt,
                      float* __restrict__ out)
{
    // [pixel][chunk^( wc&3 )][8c] — XOR swizzle keeps reads 2-way max (free).
    __shared__ __hip_bfloat16 xs[10 * 34 * 64];     // 43,520 B -> 3 blocks/CU
    const int ow0 = blockIdx.x * 32;
    const int oh0 = blockIdx.y * 8;
    const int co0 = blockIdx.z * 64;
    const int tid = threadIdx.x;

    // Stage x tile: rows oh0..oh0+9, cols ow0..ow0+33, all 64 c (bf16).
    for (int q = tid; q < 10 * 34 * 8; q += 256) {
        int sub = q & 7;
        int pix = q >> 3;
        int row = pix / 34;
        int wc  = pix - row * 34;
        int chunk = sub ^ (wc & 3);
        *(float4*)(xs + pix * 64 + chunk * 8) =
            *(const float4*)(xt + ((oh0 + row) * XP + (ow0 + wc)) * 64 + sub * 8);
    }
    __syncthreads();   // the only barrier

    const int wave = tid >> 6;
    const int lane = tid & 63;
    const int n    = lane & 31;     // A: co offset; B: ow offset; D: col
    const int h    = lane >> 5;     // k-half selector
    const int r0   = wave * 2;      // this wave's 2 output rows

    f32x16 acc[2][2] = {};          // [mi][ni]

    #pragma unroll
    for (int p = 0; p < 9; ++p) {   // tap = i*3 + jj; fully unrolled, no barriers
        const int i  = p / 3;
        const int jj = p - i * 3;

        // 8 independent, coalesced, L1/L2-hot global loads (batched).
        bf16x8 afr[4][2];
        #pragma unroll
        for (int t = 0; t < 4; ++t)
            #pragma unroll
            for (int mi = 0; mi < 2; ++mi)
                afr[t][mi] = *(const bf16x8*)(wt +
                    ((p * 8 + t * 2 + h) * 128 + co0 + mi * 32 + n) * 8);

        #pragma unroll
        for (int t = 0; t < 4; ++t) {
            bf16x8 bfr[2];
            #pragma unroll
            for (int ni = 0; ni < 2; ++ni) {
                const int wc    = n + jj;
                const int pix   = (i + r0 + ni) * 34 + wc;
                const int chunk = (t * 2 + h) ^ (wc & 3);
                bfr[ni] = *(const bf16x8*)(xs + pix * 64 + chunk * 8);
            }
            #pragma unroll
            for (int mi = 0; mi < 2; ++mi)
                #pragma unroll
                for (int ni = 0; ni < 2; ++ni)
                    acc[mi][ni] = __builtin_amdgcn_mfma_f32_32x32x16_bf16(
                        afr[t][mi], bfr[ni], acc[mi][ni], 0, 0, 0);
        }
    }

    // Epilogue: lanes 0..31 = 32 consecutive ow -> 128B full-line stores.
    #pragma unroll
    for (int mi = 0; mi < 2; ++mi) {
        #pragma unroll
        for (int ni = 0; ni < 2; ++ni) {
            const int oh = oh0 + r0 + ni;
            const int ow = ow0 + n;
            if (oh < H_OUT && ow < W_OUT) {
                #pragma unroll
                for (int r = 0; r < 16; ++r) {
                    int co = co0 + mi * 32 + (r & 3) + 8 * (r >> 2) + 4 * h;
                    out[(size_t)co * (H_OUT * W_OUT) + oh * W_OUT + ow] = acc[mi][ni][r];
                }
            }
        }
    }
}

extern "C" void kernel_launch(void* const* d_in, const int* in_sizes, int n_in,
                              void* d_out, int out_size, void* d_ws, size_t ws_size,
                              hipStream_t stream)
{
    const float* x = (const float*)d_in[0];
    const float* w = (const float*)d_in[1];
    float* out     = (float*)d_out;

    __hip_bfloat16* xt = (__hip_bfloat16*)d_ws;                      // 226*226*64*2 B
    __hip_bfloat16* wt = (__hip_bfloat16*)((char*)d_ws + (size_t)XP * XP * 64 * 2);

    transform_w_kernel<<<288, 256, 0, stream>>>(w, wt);
    transpose_x_kernel<<<dim3(4, XP), 256, 0, stream>>>(x, xt);
    conv_mfma_kernel<<<dim3(7, 28, 2), 256, 0, stream>>>(xt, wt, out);
}

// Round 13
// 90.684 us; speedup vs baseline: 1.4286x; 1.0138x over previous
//
#include <hip/hip_runtime.h>
#include <hip/hip_bf16.h>

// 3x3 VALID conv via bf16 MFMA implicit GEMM.
// x: (64,224,224) fp32, w: (128,64,3,3) fp32, out: (128,222,222) fp32.
//
// R13: R12 (zero-LDS / zero-barrier streaming conv) with the one-line fix:
// conv B-load row index now includes oh0 (R12 read rows 0..9 for every
// block -> absmax 177.5). Design rationale unchanged: R7/R9/R11 all landed
// 18-22us regardless of staging design while throughput models say 3-8 ->
// the stage/barrier structure was the binder. Both operands are
// lane-contiguous in global ([ij][kstep][co][c8] for A, [h][chunk][w][c8]
// for B); per tap 16 independent dwordx4 + 16 MFMAs, fully unrolled,
// no __syncthreads -> compiler vmcnt-pipelines loads across taps.
// A: m=lane&31(co), k=(lane>>5)*8+j. B: n=lane&31(ow). D: col=lane&31,
// row=(reg&3)+8*(reg>>2)+4*(lane>>5)  [R9/R11-validated].

#define H_IN   224
#define W_IN   224
#define C_OUT  128
#define H_OUT  222
#define W_OUT  222
#define XP     226   // padded spatial extent of xt
#define TW     68    // padded w stride in transpose LDS

typedef __attribute__((ext_vector_type(8)))  short bf16x8;
typedef __attribute__((ext_vector_type(16))) float f32x16;

static __device__ __forceinline__ unsigned short f2bs(float f) {
    union { __hip_bfloat16 h; unsigned short u; } cv;
    cv.h = __float2bfloat16(f);
    return cv.u;
}

// wt layout: [ij][kstep(=c>>3)][co][c&7]  -> A-fragment reads lane-contiguous.
__global__ __launch_bounds__(256)
void transform_w_kernel(const float* __restrict__ w, __hip_bfloat16* __restrict__ wt)
{
    int idx = blockIdx.x * 256 + threadIdx.x;     // 9*128*64 = 73,728
    if (idx < 9 * 128 * 64) {
        int ij  = idx >> 13;
        int rem = idx & 8191;
        int co  = rem >> 6;
        int c   = rem & 63;
        wt[((ij * 8 + (c >> 3)) * 128 + co) * 8 + (c & 7)] =
            __float2bfloat16(w[(co * 64 + c) * 9 + ij]);
    }
}

// xt layout: [h][chunk(=c>>3)][w][c&7] in 16B units: unit index
// (h*8 + chunk)*XP + w. B-fragment loads become lane-contiguous global reads.
__global__ __launch_bounds__(256)
void transpose_x_kernel(const float* __restrict__ x, float4* __restrict__ xt4)
{
    __shared__ __align__(16) unsigned short tile[64 * TW];   // [c][w_local]
    const int h  = blockIdx.y;                 // 0..225
    const int w0 = blockIdx.x * 64;            // 0,64,128,192
    const int t  = threadIdx.x;

    // Phase 1: coalesced float4 reads along w; zeros for padded h/w.
    {
        const int wq = (t & 15) * 4;           // 0..60 (lanes contiguous in w)
        const int c0 = t >> 4;                 // 0..15
        #pragma unroll
        for (int p = 0; p < 4; ++p) {
            const int c  = c0 + p * 16;
            const int wg = w0 + wq;
            float4 v = make_float4(0.f, 0.f, 0.f, 0.f);
            if (h < H_IN && wg < W_IN)         // wg%4==0, W_IN%4==0 -> all-or-nothing
                v = *(const float4*)(x + ((size_t)c * H_IN + h) * W_IN + wg);
            ushort4 b;
            b.x = f2bs(v.x); b.y = f2bs(v.y); b.z = f2bs(v.z); b.w = f2bs(v.w);
            *(ushort4*)(tile + c * TW + wq) = b;   // (c*136 + wq*2) % 8 == 0
        }
    }
    __syncthreads();

    // Phase 2: gather 16 c per thread from LDS, two chunk-separated 16B stores.
    {
        const int wl = t >> 2;                 // 0..63
        const int cq = (t & 3) * 16;           // 0,16,32,48
        const int ch = (t & 3) * 2;            // chunk = c>>3
        const int wg = w0 + wl;
        if (wg < XP) {
            alignas(16) unsigned short r[16];
            #pragma unroll
            for (int k = 0; k < 16; ++k)
                r[k] = tile[(cq + k) * TW + wl];
            xt4[((size_t)h * 8 + ch)     * XP + wg] = ((const float4*)r)[0];
            xt4[((size_t)h * 8 + ch + 1) * XP + wg] = ((const float4*)r)[1];
        }
    }
}

__global__ __launch_bounds__(256)
void conv_mfma_kernel(const float4* __restrict__ xt4,
                      const __hip_bfloat16* __restrict__ wt,
                      float* __restrict__ out)
{
    const int ow0 = blockIdx.x * 32;
    const int oh0 = blockIdx.y * 8;
    const int co0 = blockIdx.z * 64;
    const int tid = threadIdx.x;

    const int wave = tid >> 6;
    const int lane = tid & 63;
    const int n    = lane & 31;     // A: co offset; B: ow offset; D: col
    const int h    = lane >> 5;     // k-half selector
    const int r0   = wave * 2;      // this wave's 2 output rows

    f32x16 acc[2][2] = {};          // [mi][ni]

    #pragma unroll
    for (int p = 0; p < 9; ++p) {   // tap = i*3 + jj; no barriers anywhere
        const int i  = p / 3;
        const int jj = p - i * 3;

        // 8 A-loads + 8 B-loads, all independent, all lane-contiguous.
        bf16x8 afr[4][2];
        bf16x8 bfr[4][2];
        #pragma unroll
        for (int t = 0; t < 4; ++t) {
            #pragma unroll
            for (int mi = 0; mi < 2; ++mi)
                afr[t][mi] = *(const bf16x8*)(wt +
                    ((p * 8 + t * 2 + h) * 128 + co0 + mi * 32 + n) * 8);
            #pragma unroll
            for (int ni = 0; ni < 2; ++ni) {
                const int row = oh0 + r0 + ni + i;    // FIX: oh0 was missing in R12
                const int ch  = t * 2 + h;
                bfr[t][ni] = *(const bf16x8*)(xt4 +
                    ((size_t)row * 8 + ch) * XP + ow0 + n + jj);
            }
        }

        #pragma unroll
        for (int t = 0; t < 4; ++t)
            #pragma unroll
            for (int mi = 0; mi < 2; ++mi)
                #pragma unroll
                for (int ni = 0; ni < 2; ++ni)
                    acc[mi][ni] = __builtin_amdgcn_mfma_f32_32x32x16_bf16(
                        afr[t][mi], bfr[t][ni], acc[mi][ni], 0, 0, 0);
    }

    // Epilogue: lanes 0..31 = 32 consecutive ow -> 128B full-line stores.
    #pragma unroll
    for (int mi = 0; mi < 2; ++mi) {
        #pragma unroll
        for (int ni = 0; ni < 2; ++ni) {
            const int oh = oh0 + r0 + ni;
            const int ow = ow0 + n;
            if (oh < H_OUT && ow < W_OUT) {
                #pragma unroll
                for (int r = 0; r < 16; ++r) {
                    int co = co0 + mi * 32 + (r & 3) + 8 * (r >> 2) + 4 * h;
                    out[(size_t)co * (H_OUT * W_OUT) + oh * W_OUT + ow] = acc[mi][ni][r];
                }
            }
        }
    }
}

extern "C" void kernel_launch(void* const* d_in, const int* in_sizes, int n_in,
                              void* d_out, int out_size, void* d_ws, size_t ws_size,
                              hipStream_t stream)
{
    const float* x = (const float*)d_in[0];
    const float* w = (const float*)d_in[1];
    float* out     = (float*)d_out;

    float4* xt4        = (float4*)d_ws;                              // 226*8*226*16 B
    __hip_bfloat16* wt = (__hip_bfloat16*)((char*)d_ws + (size_t)XP * XP * 64 * 2);

    transform_w_kernel<<<288, 256, 0, stream>>>(w, wt);
    transpose_x_kernel<<<dim3(4, XP), 256, 0, stream>>>(x, xt4);
    conv_mfma_kernel<<<dim3(7, 28, 2), 256, 0, stream>>>(xt4, wt, out);
}